// Round 6
// baseline (145.338 us; speedup 1.0000x reference)
//
#include <hip/hip_runtime.h>

namespace {
constexpr int kM = 4, kJ = 2, kI = 3, kL = 2, kW = 9;
constexpr float kInvLn2 = 1.4426950408889634f;

typedef float v2f __attribute__((ext_vector_type(2)));  // -> v_pk_*_f32

__device__ __forceinline__ float fexp2(float x) { return __builtin_amdgcn_exp2f(x); }

// dp layout (80 floats), per m (18 floats at m*18), j-packed {j0,j1} pairs:
//   [An, B0n, B1n, w0n, w1n, C00, C01, C10, C11]
// where An/B*n/w*n are quad coeffs of msN = -ms/ln2 (negated, log2-scaled):
//   msN = An + s0*(B0n + w0n*s0) + s1*(B1n + w1n*s1)
// C (head∘body, gavg-folded) unscaled. D[m][l] at 72 + m*2 + l.
__global__ void prep_kernel(const float* __restrict__ constants,
                            const float* __restrict__ gammas,
                            const float* __restrict__ W_body,
                            const float* __restrict__ b_body,
                            const float* __restrict__ W_head,
                            const float* __restrict__ b_head,
                            float* __restrict__ dp) {
  const int t = threadIdx.x;
  if (t < 8) {
    const int mj = t, m = t >> 1, j = t & 1;
    const float g0 = fminf(fmaxf(gammas[mj * kL + 0], 0.f), 1.f);
    const float g1 = fminf(fmaxf(gammas[mj * kL + 1], 0.f), 1.f);
    const float w0 = 1.f - g0, w1 = 1.f - g1;
    const float c0 = constants[mj * kL + 0], c1 = constants[mj * kL + 1];
    const float gavg = 0.5f * (g0 + g1);
    float* base = dp + m * 18;
    base[0 * 2 + j] = -(w0 * c0 * c0 + w1 * c1 * c1) * kInvLn2;  // An
    base[1 * 2 + j] = 2.f * w0 * c0 * kInvLn2;                   // B0n
    base[2 * 2 + j] = 2.f * w1 * c1 * kInvLn2;                   // B1n
    base[3 * 2 + j] = -w0 * kInvLn2;                             // w0n
    base[4 * 2 + j] = -w1 * kInvLn2;                             // w1n
    for (int l = 0; l < kL; ++l)
      for (int lp = 0; lp < kL; ++lp) {
        float acc = 0.f;
        for (int i = 0; i < kI; ++i)
          acc += W_head[(m * kL + l) * kI + i] * W_body[(mj * kI + i) * kL + lp];
        base[(5 + l * kL + lp) * 2 + j] = gavg * acc;            // C[l][lp]
      }
  } else if (t < 12) {
    const int m = t - 8;
    for (int l = 0; l < kL; ++l) {
      float d = b_head[m * kL + l];
      for (int j = 0; j < kJ; ++j) {
        const int mj = m * kJ + j;
        const float g0 = fminf(fmaxf(gammas[mj * kL + 0], 0.f), 1.f);
        const float g1 = fminf(fmaxf(gammas[mj * kL + 1], 0.f), 1.f);
        const float gavg = 0.5f * (g0 + g1);
        float acc = 0.f;
        for (int i = 0; i < kI; ++i)
          acc += W_head[(m * kL + l) * kI + i] * b_body[mj * kI + i];
        d += gavg * acc;
      }
      dp[72 + m * kL + l] = d;
    }
  }
}

// 1 element/thread, no LDS, params via wave-uniform scalar loads.
// __launch_bounds__(256, 8): force VGPR<=64 -> 32 waves/CU (2x the >64 cliff).
__global__ __launch_bounds__(256, 8) void algelogic_main(
    const float* __restrict__ state, const float* __restrict__ dp,
    float* __restrict__ out) {
  const int b = blockIdx.x * 256 + threadIdx.x;
  const float2* sr = reinterpret_cast<const float2*>(state) + (size_t)b * kW;

  v2f s[kW];
#pragma unroll
  for (int w = 0; w < kW; ++w) {
    const float2 v = sr[w];
    v2f t; t.x = v.x; t.y = v.y;
    s[w] = t;
  }

  float Cs = 0.f, X0 = 0.f, X1 = 0.f, K = 0.f;

#pragma unroll
  for (int m = 0; m < kM; ++m) {
    const float* P = dp + m * 18;   // uniform -> s_load
    v2f A, B0, B1, w0, w1;
    A.x = P[0];  A.y = P[1];
    B0.x = P[2]; B0.y = P[3];
    B1.x = P[4]; B1.y = P[5];
    w0.x = P[6]; w0.y = P[7];
    w1.x = P[8]; w1.y = P[9];

    v2f psum = {1e-35f, 1e-35f};   // guard: rcp never sees denormal/0
    v2f pb0 = {0.f, 0.f}, pb1 = {0.f, 0.f}, pmq = {0.f, 0.f};
#pragma unroll
    for (int w = 0; w < kW; ++w) {
      const v2f sw = s[w];
      const v2f t0 = B0 + w0 * sw.x;
      const v2f t1 = B1 + w1 * sw.y;
      v2f msN = A + t0 * sw.x;
      msN += t1 * sw.y;              // msN = -ms/ln2 <= 0
      v2f e; e.x = fexp2(msN.x); e.y = fexp2(msN.y);
      psum += e;
      pb0 += e * sw.x;
      pb1 += e * sw.y;
      pmq += e * msN;                // = -Σ e·ms/ln2
    }

    v2f rinv;
    rinv.x = __builtin_amdgcn_rcpf(psum.x);
    rinv.y = __builtin_amdgcn_rcpf(psum.y);
    const v2f bb0 = pb0 * rinv, bb1 = pb1 * rinv;
    const v2f mqv = pmq * rinv;
    const float conf = fexp2(mqv.x + mqv.y);   // exp2(-mq/ln2) = exp(-mq)

    v2f C00, C01, C10, C11;
    C00.x = P[10]; C00.y = P[11];
    C01.x = P[12]; C01.y = P[13];
    C10.x = P[14]; C10.y = P[15];
    C11.x = P[16]; C11.y = P[17];
    const v2f t0 = C00 * bb0 + C01 * bb1;
    const v2f t1 = C10 * bb0 + C11 * bb1;
    const float r0 = dp[72 + m * 2 + 0] + t0.x + t0.y;
    const float r1 = dp[72 + m * 2 + 1] + t1.x + t1.y;

    Cs += conf;
    X0 = fmaf(conf, r0, X0);
    X1 = fmaf(conf, r1, X1);
    K = fmaf(conf, fmaf(r0, r0, r1 * r1), K);
  }

  const float X02 = 2.f * X0, X12 = 2.f * X1;
  float* orow = out + (size_t)b * kW;
#pragma unroll
  for (int w = 0; w < kW; ++w) {
    const v2f q = s[w] * s[w];
    // out = 2X0*s0 + 2X1*s1 - Cs*(s0^2+s1^2) - K
    orow[w] = fmaf(X02, s[w].x, fmaf(X12, s[w].y, fmaf(-Cs, q.x + q.y, -K)));
  }
}
}  // namespace

extern "C" void kernel_launch(void* const* d_in, const int* in_sizes, int n_in,
                              void* d_out, int out_size, void* d_ws, size_t ws_size,
                              hipStream_t stream) {
  const float* state     = (const float*)d_in[0];
  const float* constants = (const float*)d_in[1];
  const float* gammas    = (const float*)d_in[2];
  const float* W_body    = (const float*)d_in[3];
  const float* b_body    = (const float*)d_in[4];
  const float* W_head    = (const float*)d_in[5];
  const float* b_head    = (const float*)d_in[6];
  float* out = (float*)d_out;
  float* dp  = (float*)d_ws;

  const int B = in_sizes[0] / (kW * kL);   // 1048576
  hipLaunchKernelGGL(prep_kernel, dim3(1), dim3(64), 0, stream,
                     constants, gammas, W_body, b_body, W_head, b_head, dp);
  hipLaunchKernelGGL(algelogic_main, dim3(B / 256), dim3(256), 0, stream,
                     state, dp, out);
}

// Round 7
// 86.651 us; speedup vs baseline: 1.6773x; 1.6773x over previous
//
#include <hip/hip_runtime.h>

namespace {
constexpr int kM = 4, kJ = 2, kI = 3, kL = 2, kW = 9;
constexpr float kInvLn2 = 1.4426950408889634f;

typedef float v2f __attribute__((ext_vector_type(2)));  // -> v_pk_*_f32

__device__ __forceinline__ float fexp2(float x) { return __builtin_amdgcn_exp2f(x); }

// dp layout (72 floats), per m (16 floats at m*16), j-packed {j0,j1} pairs:
//   [c0, c1, w0n, w1n, C00, C01, C10, C11]
// completed-square match score (negated, log2-scaled):
//   msN = w0n*(s0-c0)^2 + w1n*(s1-c1)^2  with w*n = -(1-g*)/ln2  (msN <= 0)
// C (head∘body, gavg-folded) unscaled. D[m][l] at 64 + m*2 + l.
__global__ void prep_kernel(const float* __restrict__ constants,
                            const float* __restrict__ gammas,
                            const float* __restrict__ W_body,
                            const float* __restrict__ b_body,
                            const float* __restrict__ W_head,
                            const float* __restrict__ b_head,
                            float* __restrict__ dp) {
  const int t = threadIdx.x;
  if (t < 8) {
    const int mj = t, m = t >> 1, j = t & 1;
    const float g0 = fminf(fmaxf(gammas[mj * kL + 0], 0.f), 1.f);
    const float g1 = fminf(fmaxf(gammas[mj * kL + 1], 0.f), 1.f);
    const float w0 = 1.f - g0, w1 = 1.f - g1;
    const float c0 = constants[mj * kL + 0], c1 = constants[mj * kL + 1];
    const float gavg = 0.5f * (g0 + g1);
    float* base = dp + m * 16;
    base[0 * 2 + j] = c0;                 // c0
    base[1 * 2 + j] = c1;                 // c1
    base[2 * 2 + j] = -w0 * kInvLn2;      // w0n
    base[3 * 2 + j] = -w1 * kInvLn2;      // w1n
    for (int l = 0; l < kL; ++l)
      for (int lp = 0; lp < kL; ++lp) {
        float acc = 0.f;
        for (int i = 0; i < kI; ++i)
          acc += W_head[(m * kL + l) * kI + i] * W_body[(mj * kI + i) * kL + lp];
        base[(4 + l * kL + lp) * 2 + j] = gavg * acc;   // C[l][lp]
      }
  } else if (t < 12) {
    const int m = t - 8;
    for (int l = 0; l < kL; ++l) {
      float d = b_head[m * kL + l];
      for (int j = 0; j < kJ; ++j) {
        const int mj = m * kJ + j;
        const float g0 = fminf(fmaxf(gammas[mj * kL + 0], 0.f), 1.f);
        const float g1 = fminf(fmaxf(gammas[mj * kL + 1], 0.f), 1.f);
        const float gavg = 0.5f * (g0 + g1);
        float acc = 0.f;
        for (int i = 0; i < kI; ++i)
          acc += W_head[(m * kL + l) * kI + i] * b_body[mj * kI + i];
        d += gavg * acc;
      }
      dp[64 + m * kL + l] = d;
    }
  }
}

// 1 elem/thread. Params stay in SGPRs: every pk op reads at most ONE uniform
// pair (completed-square form), so no VGPR param copies. Target ~45 VGPR ->
// fits the 64-reg cap of __launch_bounds__(256,8) -> 32 waves/CU, no spills.
__global__ __launch_bounds__(256, 8) void algelogic_main(
    const float* __restrict__ state, const float* __restrict__ dp,
    float* __restrict__ out) {
  const int b = blockIdx.x * 256 + threadIdx.x;
  const float2* sr = reinterpret_cast<const float2*>(state) + (size_t)b * kW;

  v2f s[kW];
#pragma unroll
  for (int w = 0; w < kW; ++w) {
    const float2 v = sr[w];
    v2f t; t.x = v.x; t.y = v.y;
    s[w] = t;
  }

  float Cs = 0.f, X0 = 0.f, X1 = 0.f, K = 0.f;

#pragma unroll
  for (int m = 0; m < kM; ++m) {
    const float* P = dp + m * 16;          // uniform -> s_load
    v2f c0;  c0.x = P[0];  c0.y = P[1];
    v2f c1;  c1.x = P[2];  c1.y = P[3];
    v2f w0n; w0n.x = P[4]; w0n.y = P[5];
    v2f w1n; w1n.x = P[6]; w1n.y = P[7];

    v2f psum = {1e-35f, 1e-35f};   // guard: rcp never sees denormal/0
    v2f pb0 = {0.f, 0.f}, pb1 = {0.f, 0.f}, pmq = {0.f, 0.f};
#pragma unroll
    for (int w = 0; w < kW; ++w) {
      const float sx = s[w].x, sy = s[w].y;
      const v2f d0 = sx - c0;              // pk_sub (1 sgpr-pair)
      const v2f d1 = sy - c1;
      v2f msN = (d0 * d0) * w0n;           // pk_mul, pk_mul (1 sgpr-pair)
      msN += (d1 * d1) * w1n;              // pk_mul, pk_fma-ish
      v2f e; e.x = fexp2(msN.x); e.y = fexp2(msN.y);
      psum += e;
      pb0 += e * sx;
      pb1 += e * sy;
      pmq += e * msN;                      // = -Σ e·ms/ln2
    }

    v2f rinv;
    rinv.x = __builtin_amdgcn_rcpf(psum.x);
    rinv.y = __builtin_amdgcn_rcpf(psum.y);
    const v2f bb0 = pb0 * rinv, bb1 = pb1 * rinv;
    const v2f mqv = pmq * rinv;
    const float conf = fexp2(mqv.x + mqv.y);   // exp2(-mq/ln2) = exp(-mq)

    v2f C00; C00.x = P[8];  C00.y = P[9];
    v2f C01; C01.x = P[10]; C01.y = P[11];
    v2f C10; C10.x = P[12]; C10.y = P[13];
    v2f C11; C11.x = P[14]; C11.y = P[15];
    const v2f t0 = C00 * bb0 + C01 * bb1;      // each pk op: 1 uniform pair
    const v2f t1 = C10 * bb0 + C11 * bb1;
    const float r0 = dp[64 + m * 2 + 0] + t0.x + t0.y;
    const float r1 = dp[64 + m * 2 + 1] + t1.x + t1.y;

    Cs += conf;
    X0 = fmaf(conf, r0, X0);
    X1 = fmaf(conf, r1, X1);
    K = fmaf(conf, fmaf(r0, r0, r1 * r1), K);
  }

  const float X02 = 2.f * X0, X12 = 2.f * X1;
  float* orow = out + (size_t)b * kW;
#pragma unroll
  for (int w = 0; w < kW; ++w) {
    const v2f q = s[w] * s[w];
    // out = 2X0*s0 + 2X1*s1 - Cs*(s0^2+s1^2) - K
    orow[w] = fmaf(X02, s[w].x, fmaf(X12, s[w].y, fmaf(-Cs, q.x + q.y, -K)));
  }
}
}  // namespace

extern "C" void kernel_launch(void* const* d_in, const int* in_sizes, int n_in,
                              void* d_out, int out_size, void* d_ws, size_t ws_size,
                              hipStream_t stream) {
  const float* state     = (const float*)d_in[0];
  const float* constants = (const float*)d_in[1];
  const float* gammas    = (const float*)d_in[2];
  const float* W_body    = (const float*)d_in[3];
  const float* b_body    = (const float*)d_in[4];
  const float* W_head    = (const float*)d_in[5];
  const float* b_head    = (const float*)d_in[6];
  float* out = (float*)d_out;
  float* dp  = (float*)d_ws;

  const int B = in_sizes[0] / (kW * kL);   // 1048576
  hipLaunchKernelGGL(prep_kernel, dim3(1), dim3(64), 0, stream,
                     constants, gammas, W_body, b_body, W_head, b_head, dp);
  hipLaunchKernelGGL(algelogic_main, dim3(B / 256), dim3(256), 0, stream,
                     state, dp, out);
}

// Round 8
// 34.401 us; speedup vs baseline: 4.2248x; 2.5189x over previous
//
#include <hip/hip_runtime.h>

namespace {
constexpr int kM = 4, kJ = 2, kI = 3, kL = 2, kW = 9;
constexpr float kInvLn2 = 1.4426950408889634f;

typedef float v2f __attribute__((ext_vector_type(2)));  // -> v_pk_*_f32

__device__ __forceinline__ float fexp2(float x) { return __builtin_amdgcn_exp2f(x); }

// dp layout (72 floats), per m (16 floats at m*16), j-packed {j0,j1} pairs:
//   [c0, c1, w0n, w1n, C00, C01, C10, C11]
// completed-square match score (negated, log2-scaled):
//   msN = w0n*(s0-c0)^2 + w1n*(s1-c1)^2  with w*n = -(1-g*)/ln2  (msN <= 0)
// C (head∘body, gavg-folded) unscaled. D[m][l] at 64 + m*2 + l.
__global__ void prep_kernel(const float* __restrict__ constants,
                            const float* __restrict__ gammas,
                            const float* __restrict__ W_body,
                            const float* __restrict__ b_body,
                            const float* __restrict__ W_head,
                            const float* __restrict__ b_head,
                            float* __restrict__ dp) {
  const int t = threadIdx.x;
  if (t < 8) {
    const int mj = t, m = t >> 1, j = t & 1;
    const float g0 = fminf(fmaxf(gammas[mj * kL + 0], 0.f), 1.f);
    const float g1 = fminf(fmaxf(gammas[mj * kL + 1], 0.f), 1.f);
    const float w0 = 1.f - g0, w1 = 1.f - g1;
    const float c0 = constants[mj * kL + 0], c1 = constants[mj * kL + 1];
    const float gavg = 0.5f * (g0 + g1);
    float* base = dp + m * 16;
    base[0 * 2 + j] = c0;                 // c0
    base[1 * 2 + j] = c1;                 // c1
    base[2 * 2 + j] = -w0 * kInvLn2;      // w0n
    base[3 * 2 + j] = -w1 * kInvLn2;      // w1n
    for (int l = 0; l < kL; ++l)
      for (int lp = 0; lp < kL; ++lp) {
        float acc = 0.f;
        for (int i = 0; i < kI; ++i)
          acc += W_head[(m * kL + l) * kI + i] * W_body[(mj * kI + i) * kL + lp];
        base[(4 + l * kL + lp) * 2 + j] = gavg * acc;   // C[l][lp]
      }
  } else if (t < 12) {
    const int m = t - 8;
    for (int l = 0; l < kL; ++l) {
      float d = b_head[m * kL + l];
      for (int j = 0; j < kJ; ++j) {
        const int mj = m * kJ + j;
        const float g0 = fminf(fmaxf(gammas[mj * kL + 0], 0.f), 1.f);
        const float g1 = fminf(fmaxf(gammas[mj * kL + 1], 0.f), 1.f);
        const float gavg = 0.5f * (g0 + g1);
        float acc = 0.f;
        for (int i = 0; i < kI; ++i)
          acc += W_head[(m * kL + l) * kI + i] * b_body[mj * kI + i];
        d += gavg * acc;
      }
      dp[64 + m * kL + l] = d;
    }
  }
}

// 1 elem/thread, no LDS; params via wave-uniform scalar loads (SGPRs).
// __launch_bounds__(256, 4): hipcc's cap model is 256/waves -> 64-VGPR cap.
// Live set ~45-50 fits 64 with NO spills; HW still runs 8 waves/SIMD at
// VGPR<=64 (occupancy halves only above 64 — measured m69).
__global__ __launch_bounds__(256, 4) void algelogic_main(
    const float* __restrict__ state, const float* __restrict__ dp,
    float* __restrict__ out) {
  const int b = blockIdx.x * 256 + threadIdx.x;
  const float2* sr = reinterpret_cast<const float2*>(state) + (size_t)b * kW;

  v2f s[kW];
#pragma unroll
  for (int w = 0; w < kW; ++w) {
    const float2 v = sr[w];
    v2f t; t.x = v.x; t.y = v.y;
    s[w] = t;
  }

  float Cs = 0.f, X0 = 0.f, X1 = 0.f, K = 0.f;

#pragma unroll
  for (int m = 0; m < kM; ++m) {
    const float* P = dp + m * 16;          // uniform -> s_load
    v2f c0;  c0.x = P[0];  c0.y = P[1];
    v2f c1;  c1.x = P[2];  c1.y = P[3];
    v2f w0n; w0n.x = P[4]; w0n.y = P[5];
    v2f w1n; w1n.x = P[6]; w1n.y = P[7];

    v2f psum = {1e-35f, 1e-35f};   // guard: rcp never sees denormal/0
    v2f pb0 = {0.f, 0.f}, pb1 = {0.f, 0.f}, pmq = {0.f, 0.f};
#pragma unroll
    for (int w = 0; w < kW; ++w) {
      const float sx = s[w].x, sy = s[w].y;
      const v2f d0 = sx - c0;              // pk ops: at most 1 sgpr-pair each
      const v2f d1 = sy - c1;
      v2f msN = (d0 * d0) * w0n;
      msN += (d1 * d1) * w1n;
      v2f e; e.x = fexp2(msN.x); e.y = fexp2(msN.y);
      psum += e;
      pb0 += e * sx;
      pb1 += e * sy;
      pmq += e * msN;                      // = -Σ e·ms/ln2
    }

    v2f rinv;
    rinv.x = __builtin_amdgcn_rcpf(psum.x);
    rinv.y = __builtin_amdgcn_rcpf(psum.y);
    const v2f bb0 = pb0 * rinv, bb1 = pb1 * rinv;
    const v2f mqv = pmq * rinv;
    const float conf = fexp2(mqv.x + mqv.y);   // exp2(-mq/ln2) = exp(-mq)

    v2f C00; C00.x = P[8];  C00.y = P[9];
    v2f C01; C01.x = P[10]; C01.y = P[11];
    v2f C10; C10.x = P[12]; C10.y = P[13];
    v2f C11; C11.x = P[14]; C11.y = P[15];
    const v2f t0 = C00 * bb0 + C01 * bb1;
    const v2f t1 = C10 * bb0 + C11 * bb1;
    const float r0 = dp[64 + m * 2 + 0] + t0.x + t0.y;
    const float r1 = dp[64 + m * 2 + 1] + t1.x + t1.y;

    Cs += conf;
    X0 = fmaf(conf, r0, X0);
    X1 = fmaf(conf, r1, X1);
    K = fmaf(conf, fmaf(r0, r0, r1 * r1), K);
  }

  const float X02 = 2.f * X0, X12 = 2.f * X1;
  float* orow = out + (size_t)b * kW;
#pragma unroll
  for (int w = 0; w < kW; ++w) {
    const v2f q = s[w] * s[w];
    // out = 2X0*s0 + 2X1*s1 - Cs*(s0^2+s1^2) - K
    orow[w] = fmaf(X02, s[w].x, fmaf(X12, s[w].y, fmaf(-Cs, q.x + q.y, -K)));
  }
}
}  // namespace

extern "C" void kernel_launch(void* const* d_in, const int* in_sizes, int n_in,
                              void* d_out, int out_size, void* d_ws, size_t ws_size,
                              hipStream_t stream) {
  const float* state     = (const float*)d_in[0];
  const float* constants = (const float*)d_in[1];
  const float* gammas    = (const float*)d_in[2];
  const float* W_body    = (const float*)d_in[3];
  const float* b_body    = (const float*)d_in[4];
  const float* W_head    = (const float*)d_in[5];
  const float* b_head    = (const float*)d_in[6];
  float* out = (float*)d_out;
  float* dp  = (float*)d_ws;

  const int B = in_sizes[0] / (kW * kL);   // 1048576
  hipLaunchKernelGGL(prep_kernel, dim3(1), dim3(64), 0, stream,
                     constants, gammas, W_body, b_body, W_head, b_head, dp);
  hipLaunchKernelGGL(algelogic_main, dim3(B / 256), dim3(256), 0, stream,
                     state, dp, out);
}